// Round 1
// baseline (450.627 us; speedup 1.0000x reference)
//
#include <hip/hip_runtime.h>
#include <math.h>

#define H 1024
#define V 50257
#define L 512

__device__ inline float wave_reduce_sum(float v) {
    #pragma unroll
    for (int off = 32; off > 0; off >>= 1)
        v += __shfl_down(v, off, 64);
    return v;
}

__device__ inline float wave_reduce_max(float v) {
    #pragma unroll
    for (int off = 32; off > 0; off >>= 1)
        v = fmaxf(v, __shfl_down(v, off, 64));
    return v;
}

// scores[l] = dot(attn_W[l, :2048], [emb[x], h0]) + attn_b[l]
__global__ void scores_kernel(const int* __restrict__ x,
                              const float* __restrict__ emb,
                              const float* __restrict__ hidden,
                              const float* __restrict__ attn_W,
                              const float* __restrict__ attn_b,
                              float* __restrict__ scores) {
    const int l = blockIdx.x;
    const int t = threadIdx.x;              // 256
    const int xi = x[0];
    const float* wrow = attn_W + (size_t)l * (2 * H);
    float acc = 0.f;
    #pragma unroll
    for (int k = 0; k < 8; ++k) {
        int j = t + k * 256;
        float a = (j < H) ? emb[(size_t)xi * H + j] : hidden[j - H];
        acc += a * wrow[j];
    }
    __shared__ float sm[4];
    acc = wave_reduce_sum(acc);
    if ((t & 63) == 0) sm[t >> 6] = acc;
    __syncthreads();
    if (t == 0)
        scores[l] = sm[0] + sm[1] + sm[2] + sm[3] + attn_b[l];
}

// softmax over 512 scores -> attnw (ws) and d_out[V..V+L)
__global__ void softmax512(const float* __restrict__ scores,
                           float* __restrict__ attnw,
                           float* __restrict__ out_attn) {
    const int t = threadIdx.x;              // 512
    __shared__ float sm[8];
    float v = scores[t];
    float m = wave_reduce_max(v);
    if ((t & 63) == 0) sm[t >> 6] = m;
    __syncthreads();
    float M = sm[0];
    #pragma unroll
    for (int i = 1; i < 8; ++i) M = fmaxf(M, sm[i]);
    float e = expf(v - M);
    __syncthreads();
    float s = wave_reduce_sum(e);
    if ((t & 63) == 0) sm[t >> 6] = s;
    __syncthreads();
    float S = 0.f;
    #pragma unroll
    for (int i = 0; i < 8; ++i) S += sm[i];
    float w = e / S;
    attnw[t] = w;
    out_attn[t] = w;
}

// attnap[h] = sum_l attnw[l] * enc[l*H + h]
__global__ void attn_apply(const float* __restrict__ attnw,
                           const float* __restrict__ enc,
                           float* __restrict__ attnap) {
    const int h = blockIdx.x * blockDim.x + threadIdx.x;   // 1024 threads
    float acc = 0.f;
    for (int l = 0; l < L; ++l)
        acc += attnw[l] * enc[(size_t)l * H + h];
    attnap[h] = acc;
}

// gru_in[r] = relu(dot(comb_W[r, :2048], [emb[x], attnap]) + comb_b[r])
__global__ void combine_relu(const int* __restrict__ x,
                             const float* __restrict__ emb,
                             const float* __restrict__ attnap,
                             const float* __restrict__ comb_W,
                             const float* __restrict__ comb_b,
                             float* __restrict__ gru_in) {
    const int r = blockIdx.x;
    const int t = threadIdx.x;              // 256
    const int xi = x[0];
    const float* wrow = comb_W + (size_t)r * (2 * H);
    float acc = 0.f;
    #pragma unroll
    for (int k = 0; k < 8; ++k) {
        int j = t + k * 256;
        float a = (j < H) ? emb[(size_t)xi * H + j] : attnap[j - H];
        acc += a * wrow[j];
    }
    __shared__ float sm[4];
    acc = wave_reduce_sum(acc);
    if ((t & 63) == 0) sm[t >> 6] = acc;
    __syncthreads();
    if (t == 0)
        gru_in[r] = fmaxf(sm[0] + sm[1] + sm[2] + sm[3] + comb_b[r], 0.f);
}

// rows 0..3071: gx[i] = dot(W_ih[i], gru_in)+b_ih[i]; rows 3072..6143: gh
__global__ void gates_kernel(const float* __restrict__ W_ih,
                             const float* __restrict__ W_hh,
                             const float* __restrict__ b_ih,
                             const float* __restrict__ b_hh,
                             const float* __restrict__ gru_in,
                             const float* __restrict__ hidden,
                             float* __restrict__ gx,
                             float* __restrict__ gh) {
    const int b = blockIdx.x;
    const int t = threadIdx.x;              // 256
    const float* w;
    const float* vec;
    float bias;
    float* outp;
    int r;
    if (b < 3 * H) {
        r = b; w = W_ih + (size_t)r * H; vec = gru_in; bias = b_ih[r]; outp = gx;
    } else {
        r = b - 3 * H; w = W_hh + (size_t)r * H; vec = hidden; bias = b_hh[r]; outp = gh;
    }
    float acc = 0.f;
    #pragma unroll
    for (int k = 0; k < 4; ++k) {
        int j = t + k * 256;
        acc += vec[j] * w[j];
    }
    __shared__ float sm[4];
    acc = wave_reduce_sum(acc);
    if ((t & 63) == 0) sm[t >> 6] = acc;
    __syncthreads();
    if (t == 0)
        outp[r] = sm[0] + sm[1] + sm[2] + sm[3] + bias;
}

// GRU elementwise combine (PyTorch gate order r,z,n)
__global__ void gru_cell(const float* __restrict__ gx,
                         const float* __restrict__ gh,
                         const float* __restrict__ hidden,
                         float* __restrict__ h_new) {
    const int i = blockIdx.x * blockDim.x + threadIdx.x;   // 1024 threads
    float r = 1.f / (1.f + expf(-(gx[i] + gh[i])));
    float z = 1.f / (1.f + expf(-(gx[H + i] + gh[H + i])));
    float n = tanhf(gx[2 * H + i] + r * gh[2 * H + i]);
    h_new[i] = (1.f - z) * n + z * hidden[i];
}

// logits[v] = dot(out_W[v], h_new) + out_b[v], wave-per-row, float4 loads
__global__ void logits_kernel(const float* __restrict__ out_W,
                              const float* __restrict__ out_b,
                              const float* __restrict__ h_new,
                              float* __restrict__ logits) {
    const int lid = threadIdx.x & 63;
    const int wid = threadIdx.x >> 6;
    const int v = blockIdx.x * 4 + wid;
    if (v >= V) return;
    const float4* wrow = (const float4*)(out_W + (size_t)v * H);
    const float4* hv = (const float4*)h_new;
    float acc = 0.f;
    #pragma unroll
    for (int it = 0; it < 4; ++it) {
        int idx = it * 64 + lid;
        float4 w = wrow[idx];
        float4 h = hv[idx];
        acc += w.x * h.x + w.y * h.y + w.z * h.z + w.w * h.w;
    }
    acc = wave_reduce_sum(acc);
    if (lid == 0)
        logits[v] = acc + out_b[v];
}

// single-block two-pass: red[0] = max + log(sum(exp(logit - max)))
__global__ void logsumexp_kernel(const float* __restrict__ logits,
                                 float* __restrict__ red) {
    const int t = threadIdx.x;              // 1024
    __shared__ float sm[16];
    float m = -INFINITY;
    for (int v = t; v < V; v += 1024) m = fmaxf(m, logits[v]);
    m = wave_reduce_max(m);
    if ((t & 63) == 0) sm[t >> 6] = m;
    __syncthreads();
    float M = sm[0];
    #pragma unroll
    for (int i = 1; i < 16; ++i) M = fmaxf(M, sm[i]);
    __syncthreads();
    float s = 0.f;
    for (int v = t; v < V; v += 1024) s += expf(logits[v] - M);
    s = wave_reduce_sum(s);
    if ((t & 63) == 0) sm[t >> 6] = s;
    __syncthreads();
    if (t == 0) {
        float S = 0.f;
        #pragma unroll
        for (int i = 0; i < 16; ++i) S += sm[i];
        red[0] = M + logf(S);
    }
}

__global__ void finalize_kernel(float* __restrict__ logits,
                                const float* __restrict__ red) {
    const int v = blockIdx.x * blockDim.x + threadIdx.x;
    if (v < V) logits[v] -= red[0];
}

extern "C" void kernel_launch(void* const* d_in, const int* in_sizes, int n_in,
                              void* d_out, int out_size, void* d_ws, size_t ws_size,
                              hipStream_t stream) {
    const int*   x       = (const int*)d_in[0];
    const float* enc     = (const float*)d_in[1];
    const float* hidden  = (const float*)d_in[2];
    const float* emb     = (const float*)d_in[3];
    const float* attn_W  = (const float*)d_in[4];
    const float* attn_b  = (const float*)d_in[5];
    const float* comb_W  = (const float*)d_in[6];
    const float* comb_b  = (const float*)d_in[7];
    const float* W_ih    = (const float*)d_in[8];
    const float* W_hh    = (const float*)d_in[9];
    const float* b_ih    = (const float*)d_in[10];
    const float* b_hh    = (const float*)d_in[11];
    const float* out_W   = (const float*)d_in[12];
    const float* out_b   = (const float*)d_in[13];
    float* out = (float*)d_out;
    float* ws  = (float*)d_ws;

    float* scores = ws;            // 512
    float* attnw  = ws + 512;      // 512
    float* attnap = ws + 1024;     // 1024
    float* gru_in = ws + 2048;     // 1024
    float* gx     = ws + 3072;     // 3072
    float* gh     = ws + 6144;     // 3072
    float* h_new  = ws + 9216;     // 1024
    float* red    = ws + 10240;    // 1

    scores_kernel<<<L, 256, 0, stream>>>(x, emb, hidden, attn_W, attn_b, scores);
    softmax512<<<1, L, 0, stream>>>(scores, attnw, out + V);
    attn_apply<<<H / 256, 256, 0, stream>>>(attnw, enc, attnap);
    combine_relu<<<H, 256, 0, stream>>>(x, emb, attnap, comb_W, comb_b, gru_in);
    gates_kernel<<<6 * H, 256, 0, stream>>>(W_ih, W_hh, b_ih, b_hh, gru_in, hidden, gx, gh);
    gru_cell<<<H / 256, 256, 0, stream>>>(gx, gh, hidden, h_new);
    logits_kernel<<<(V + 3) / 4, 256, 0, stream>>>(out_W, out_b, h_new, out);
    logsumexp_kernel<<<1, 1024, 0, stream>>>(out, red);
    finalize_kernel<<<(V + 255) / 256, 256, 0, stream>>>(out, red);
}

// Round 2
// 425.294 us; speedup vs baseline: 1.0596x; 1.0596x over previous
//
#include <hip/hip_runtime.h>
#include <math.h>

#define H 1024
#define V 50257
#define L 512
#define NPART ((V + 15) / 16)   // 3142 logits blocks -> (max, sumexp) partials

__device__ inline float wave_reduce_sum(float v) {
    #pragma unroll
    for (int off = 32; off > 0; off >>= 1)
        v += __shfl_down(v, off, 64);
    return v;
}

__device__ inline float wave_reduce_max(float v) {
    #pragma unroll
    for (int off = 32; off > 0; off >>= 1)
        v = fmaxf(v, __shfl_down(v, off, 64));
    return v;
}

__device__ inline float dot4(float4 a, float4 b) {
    return a.x * b.x + a.y * b.y + a.z * b.z + a.w * b.w;
}

// scores[l] = dot(attn_W[l, :2048], [emb[x], h0]) + attn_b[l]  (float4 loads)
__global__ void scores_kernel(const int* __restrict__ x,
                              const float* __restrict__ emb,
                              const float* __restrict__ hidden,
                              const float* __restrict__ attn_W,
                              const float* __restrict__ attn_b,
                              float* __restrict__ scores) {
    const int l = blockIdx.x;
    const int t = threadIdx.x;              // 256
    const int xi = x[0];
    const float4* wrow = (const float4*)(attn_W + (size_t)l * (2 * H));
    const float4* ev = (const float4*)(emb + (size_t)xi * H);
    const float4* hv = (const float4*)hidden;
    float acc = dot4(ev[t], wrow[t]) + dot4(hv[t], wrow[t + 256]);
    __shared__ float sm[4];
    acc = wave_reduce_sum(acc);
    if ((t & 63) == 0) sm[t >> 6] = acc;
    __syncthreads();
    if (t == 0)
        scores[l] = sm[0] + sm[1] + sm[2] + sm[3] + attn_b[l];
}

// softmax over 512 scores -> attnw (ws) and d_out[V..V+L); also zeroes attnap
__global__ void softmax512(const float* __restrict__ scores,
                           float* __restrict__ attnw,
                           float* __restrict__ out_attn,
                           float* __restrict__ attnap) {
    const int t = threadIdx.x;              // 512
    attnap[t] = 0.f;                        // zero accumulator for attn_apply
    attnap[t + 512] = 0.f;
    __shared__ float sm[8];
    float v = scores[t];
    float m = wave_reduce_max(v);
    if ((t & 63) == 0) sm[t >> 6] = m;
    __syncthreads();
    float M = sm[0];
    #pragma unroll
    for (int i = 1; i < 8; ++i) M = fmaxf(M, sm[i]);
    float e = expf(v - M);
    __syncthreads();
    float s = wave_reduce_sum(e);
    if ((t & 63) == 0) sm[t >> 6] = s;
    __syncthreads();
    float S = 0.f;
    #pragma unroll
    for (int i = 0; i < 8; ++i) S += sm[i];
    float w = e / S;
    attnw[t] = w;
    out_attn[t] = w;
}

// attnap[h] += sum over l-chunk of attnw[l] * enc[l*H + h]; grid (4, 8)
__global__ void attn_apply(const float* __restrict__ attnw,
                           const float* __restrict__ enc,
                           float* __restrict__ attnap) {
    const int h = blockIdx.x * 256 + threadIdx.x;
    const int l0 = blockIdx.y * 64;
    float acc = 0.f;
    #pragma unroll 8
    for (int i = 0; i < 64; ++i)
        acc += attnw[l0 + i] * enc[(size_t)(l0 + i) * H + h];
    atomicAdd(&attnap[h], acc);
}

// gru_in[r] = relu(dot(comb_W[r, :2048], [emb[x], attnap]) + comb_b[r])
__global__ void combine_relu(const int* __restrict__ x,
                             const float* __restrict__ emb,
                             const float* __restrict__ attnap,
                             const float* __restrict__ comb_W,
                             const float* __restrict__ comb_b,
                             float* __restrict__ gru_in) {
    const int r = blockIdx.x;
    const int t = threadIdx.x;              // 256
    const int xi = x[0];
    const float4* wrow = (const float4*)(comb_W + (size_t)r * (2 * H));
    const float4* ev = (const float4*)(emb + (size_t)xi * H);
    const float4* av = (const float4*)attnap;
    float acc = dot4(ev[t], wrow[t]) + dot4(av[t], wrow[t + 256]);
    __shared__ float sm[4];
    acc = wave_reduce_sum(acc);
    if ((t & 63) == 0) sm[t >> 6] = acc;
    __syncthreads();
    if (t == 0)
        gru_in[r] = fmaxf(sm[0] + sm[1] + sm[2] + sm[3] + comb_b[r], 0.f);
}

// rows 0..3071: gx[i] = dot(W_ih[i], gru_in)+b_ih[i]; rows 3072..6143: gh
__global__ void gates_kernel(const float* __restrict__ W_ih,
                             const float* __restrict__ W_hh,
                             const float* __restrict__ b_ih,
                             const float* __restrict__ b_hh,
                             const float* __restrict__ gru_in,
                             const float* __restrict__ hidden,
                             float* __restrict__ gx,
                             float* __restrict__ gh) {
    const int b = blockIdx.x;
    const int t = threadIdx.x;              // 256: exactly one float4 per thread
    const float* w;
    const float* vec;
    float bias;
    float* outp;
    int r;
    if (b < 3 * H) {
        r = b; w = W_ih + (size_t)r * H; vec = gru_in; bias = b_ih[r]; outp = gx;
    } else {
        r = b - 3 * H; w = W_hh + (size_t)r * H; vec = hidden; bias = b_hh[r]; outp = gh;
    }
    float acc = dot4(((const float4*)vec)[t], ((const float4*)w)[t]);
    __shared__ float sm[4];
    acc = wave_reduce_sum(acc);
    if ((t & 63) == 0) sm[t >> 6] = acc;
    __syncthreads();
    if (t == 0)
        outp[r] = sm[0] + sm[1] + sm[2] + sm[3] + bias;
}

// GRU elementwise combine (PyTorch gate order r,z,n)
__global__ void gru_cell(const float* __restrict__ gx,
                         const float* __restrict__ gh,
                         const float* __restrict__ hidden,
                         float* __restrict__ h_new) {
    const int i = blockIdx.x * blockDim.x + threadIdx.x;   // 1024 threads
    float r = 1.f / (1.f + expf(-(gx[i] + gh[i])));
    float z = 1.f / (1.f + expf(-(gx[H + i] + gh[H + i])));
    float n = tanhf(gx[2 * H + i] + r * gh[2 * H + i]);
    h_new[i] = (1.f - z) * n + z * hidden[i];
}

// logits[v] = dot(out_W[v], h_new) + out_b[v]; 4 rows/wave, 16 rows/block.
// Also emits per-block (max, sum(exp(x - max))) partials for log_softmax.
__global__ void logits_kernel(const float* __restrict__ out_W,
                              const float* __restrict__ out_b,
                              const float* __restrict__ h_new,
                              float* __restrict__ logits,
                              float* __restrict__ partials) {
    const int lid = threadIdx.x & 63;
    const int wid = threadIdx.x >> 6;
    __shared__ float sl[16];
    const float4* hv = (const float4*)h_new;
    float4 h0 = hv[lid], h1 = hv[64 + lid], h2 = hv[128 + lid], h3 = hv[192 + lid];
    const int vbase = blockIdx.x * 16 + wid * 4;
    #pragma unroll
    for (int rr = 0; rr < 4; ++rr) {
        const int v = vbase + rr;
        float val = -INFINITY;
        if (v < V) {                         // wave-uniform branch
            const float4* wr = (const float4*)(out_W + (size_t)v * H);
            float acc = dot4(wr[lid], h0) + dot4(wr[64 + lid], h1)
                      + dot4(wr[128 + lid], h2) + dot4(wr[192 + lid], h3);
            acc = wave_reduce_sum(acc);
            if (lid == 0) { val = acc + out_b[v]; logits[v] = val; }
        }
        if (lid == 0) sl[wid * 4 + rr] = val;
    }
    __syncthreads();
    if (threadIdx.x == 0) {
        float M = -INFINITY;
        #pragma unroll
        for (int i = 0; i < 16; ++i) M = fmaxf(M, sl[i]);
        float S = 0.f;
        #pragma unroll
        for (int i = 0; i < 16; ++i) S += expf(sl[i] - M);   // exp(-inf-M)=0
        partials[2 * blockIdx.x] = M;
        partials[2 * blockIdx.x + 1] = S;
    }
}

// Each block redundantly reduces the 3142 partials (L2-hot, ~25 KB) to the
// global logsumexp, then subtracts it from its 512-logit chunk.
__global__ void finalize_kernel(float* __restrict__ logits,
                                const float* __restrict__ partials) {
    const int t = threadIdx.x;              // 512
    __shared__ float sm[8];
    float m = -INFINITY;
    for (int i = t; i < NPART; i += 512) m = fmaxf(m, partials[2 * i]);
    m = wave_reduce_max(m);
    if ((t & 63) == 0) sm[t >> 6] = m;
    __syncthreads();
    float M = sm[0];
    #pragma unroll
    for (int i = 1; i < 8; ++i) M = fmaxf(M, sm[i]);
    __syncthreads();
    float s = 0.f;
    for (int i = t; i < NPART; i += 512) s += partials[2 * i + 1] * expf(partials[2 * i] - M);
    s = wave_reduce_sum(s);
    if ((t & 63) == 0) sm[t >> 6] = s;
    __syncthreads();
    float S = 0.f;
    #pragma unroll
    for (int i = 0; i < 8; ++i) S += sm[i];
    const float red = M + logf(S);
    const int v = blockIdx.x * 512 + t;
    if (v < V) logits[v] -= red;
}

extern "C" void kernel_launch(void* const* d_in, const int* in_sizes, int n_in,
                              void* d_out, int out_size, void* d_ws, size_t ws_size,
                              hipStream_t stream) {
    const int*   x       = (const int*)d_in[0];
    const float* enc     = (const float*)d_in[1];
    const float* hidden  = (const float*)d_in[2];
    const float* emb     = (const float*)d_in[3];
    const float* attn_W  = (const float*)d_in[4];
    const float* attn_b  = (const float*)d_in[5];
    const float* comb_W  = (const float*)d_in[6];
    const float* comb_b  = (const float*)d_in[7];
    const float* W_ih    = (const float*)d_in[8];
    const float* W_hh    = (const float*)d_in[9];
    const float* b_ih    = (const float*)d_in[10];
    const float* b_hh    = (const float*)d_in[11];
    const float* out_W   = (const float*)d_in[12];
    const float* out_b   = (const float*)d_in[13];
    float* out = (float*)d_out;
    float* ws  = (float*)d_ws;

    float* scores   = ws;            // 512
    float* attnw    = ws + 512;      // 512
    float* attnap   = ws + 1024;     // 1024
    float* gru_in   = ws + 2048;     // 1024
    float* gx       = ws + 3072;     // 3072
    float* gh       = ws + 6144;     // 3072
    float* h_new    = ws + 9216;     // 1024
    float* partials = ws + 10240;    // 2*NPART

    scores_kernel<<<L, 256, 0, stream>>>(x, emb, hidden, attn_W, attn_b, scores);
    softmax512<<<1, L, 0, stream>>>(scores, attnw, out + V, attnap);
    attn_apply<<<dim3(4, 8), 256, 0, stream>>>(attnw, enc, attnap);
    combine_relu<<<H, 256, 0, stream>>>(x, emb, attnap, comb_W, comb_b, gru_in);
    gates_kernel<<<6 * H, 256, 0, stream>>>(W_ih, W_hh, b_ih, b_hh, gru_in, hidden, gx, gh);
    gru_cell<<<H / 256, 256, 0, stream>>>(gx, gh, hidden, h_new);
    logits_kernel<<<NPART, 256, 0, stream>>>(out_W, out_b, h_new, out, partials);
    finalize_kernel<<<(V + 511) / 512, 512, 0, stream>>>(out, partials);
}

// Round 3
// 419.922 us; speedup vs baseline: 1.0731x; 1.0128x over previous
//
#include <hip/hip_runtime.h>
#include <math.h>

#define H 1024
#define V 50257
#define L 512
#define NPART ((V + 15) / 16)   // 3142 logits blocks -> (max, sumexp) partials

__device__ inline float wave_reduce_sum(float v) {
    #pragma unroll
    for (int off = 32; off > 0; off >>= 1)
        v += __shfl_down(v, off, 64);
    return v;
}

__device__ inline float wave_reduce_max(float v) {
    #pragma unroll
    for (int off = 32; off > 0; off >>= 1)
        v = fmaxf(v, __shfl_down(v, off, 64));
    return v;
}

__device__ inline float dot4(float4 a, float4 b) {
    return a.x * b.x + a.y * b.y + a.z * b.z + a.w * b.w;
}

__device__ inline float sigmoidf_(float x) { return 1.f / (1.f + expf(-x)); }

// K1: fused (a) attention scores, (b) gh = W_hh @ h0 + b_hh (input-only dep),
// (c) zero attnap accumulator. Wave-per-row, 4 rows/block.
// blocks [0,128): scores rows; blocks [128,896): gh rows; block 896: zero.
__global__ void k1_scores_gh(const int* __restrict__ x,
                             const float* __restrict__ emb,
                             const float* __restrict__ hidden,
                             const float* __restrict__ attn_W,
                             const float* __restrict__ attn_b,
                             const float* __restrict__ W_hh,
                             const float* __restrict__ b_hh,
                             float* __restrict__ scores,
                             float* __restrict__ gh,
                             float* __restrict__ attnap) {
    const int b = blockIdx.x;
    const int t = threadIdx.x;
    const int lid = t & 63, wid = t >> 6;
    const float4* hv = (const float4*)hidden;          // 256 float4
    if (b < 128) {
        const int l = b * 4 + wid;
        const int xi = x[0];
        const float4* ev = (const float4*)(emb + (size_t)xi * H);
        const float4* wrow = (const float4*)(attn_W + (size_t)l * (2 * H)); // 512 f4
        float acc = 0.f;
        #pragma unroll
        for (int k = 0; k < 4; ++k) {
            int idx = k * 64 + lid;
            acc += dot4(ev[idx], wrow[idx]);
        }
        #pragma unroll
        for (int k = 0; k < 4; ++k) {
            int idx = k * 64 + lid;
            acc += dot4(hv[idx], wrow[256 + idx]);
        }
        acc = wave_reduce_sum(acc);
        if (lid == 0) scores[l] = acc + attn_b[l];
    } else if (b < 896) {
        const int r = (b - 128) * 4 + wid;
        const float4* wrow = (const float4*)(W_hh + (size_t)r * H);  // 256 f4
        float acc = 0.f;
        #pragma unroll
        for (int k = 0; k < 4; ++k) {
            int idx = k * 64 + lid;
            acc += dot4(hv[idx], wrow[idx]);
        }
        acc = wave_reduce_sum(acc);
        if (lid == 0) gh[r] = acc + b_hh[r];
    } else {
        ((float4*)attnap)[t] = make_float4(0.f, 0.f, 0.f, 0.f);
    }
}

// K2: redundant in-block softmax (2 KB, L2-hot) + attn_apply slice.
// grid (4 h-chunks, 16 l-chunks) x 256 threads. attnap += partial.
__global__ void k2_softmax_apply(const float* __restrict__ scores,
                                 const float* __restrict__ enc,
                                 float* __restrict__ attnap,
                                 float* __restrict__ out_attn) {
    const int t = threadIdx.x;              // 256
    __shared__ float smx[4], sms[4], sw[512];
    float v0 = scores[t], v1 = scores[t + 256];
    float m = wave_reduce_max(fmaxf(v0, v1));
    if ((t & 63) == 0) smx[t >> 6] = m;
    __syncthreads();
    float M = fmaxf(fmaxf(smx[0], smx[1]), fmaxf(smx[2], smx[3]));
    float e0 = expf(v0 - M), e1 = expf(v1 - M);
    float s = wave_reduce_sum(e0 + e1);
    if ((t & 63) == 0) sms[t >> 6] = s;
    __syncthreads();
    float S = sms[0] + sms[1] + sms[2] + sms[3];
    float w0 = e0 / S, w1 = e1 / S;
    sw[t] = w0;
    sw[t + 256] = w1;
    if (blockIdx.x == 0 && blockIdx.y == 0) {
        out_attn[t] = w0;
        out_attn[t + 256] = w1;
    }
    __syncthreads();
    const int h = blockIdx.x * 256 + t;
    const int l0 = blockIdx.y * 32;
    float acc = 0.f;
    #pragma unroll 8
    for (int i = 0; i < 32; ++i)
        acc += sw[l0 + i] * enc[(size_t)(l0 + i) * H + h];
    atomicAdd(&attnap[h], acc);
}

// K3: gru_in[r] = relu(comb_W[r,:2048] . [emb[x], attnap] + comb_b[r])
// wave-per-row, 4 rows/block, 256 blocks.
__global__ void k3_combine(const int* __restrict__ x,
                           const float* __restrict__ emb,
                           const float* __restrict__ attnap,
                           const float* __restrict__ comb_W,
                           const float* __restrict__ comb_b,
                           float* __restrict__ gru_in) {
    const int t = threadIdx.x;
    const int lid = t & 63, wid = t >> 6;
    const int r = blockIdx.x * 4 + wid;
    const int xi = x[0];
    const float4* ev = (const float4*)(emb + (size_t)xi * H);
    const float4* av = (const float4*)attnap;
    const float4* wrow = (const float4*)(comb_W + (size_t)r * (2 * H));
    float acc = 0.f;
    #pragma unroll
    for (int k = 0; k < 4; ++k) {
        int idx = k * 64 + lid;
        acc += dot4(ev[idx], wrow[idx]);
    }
    #pragma unroll
    for (int k = 0; k < 4; ++k) {
        int idx = k * 64 + lid;
        acc += dot4(av[idx], wrow[256 + idx]);
    }
    acc = wave_reduce_sum(acc);
    if (lid == 0) gru_in[r] = fmaxf(acc + comb_b[r], 0.f);
}

// K4: gx[r] = W_ih[r] . gru_in + b_ih[r]; wave-per-row, 768 blocks.
__global__ void k4_gx(const float* __restrict__ W_ih,
                      const float* __restrict__ b_ih,
                      const float* __restrict__ gru_in,
                      float* __restrict__ gx) {
    const int t = threadIdx.x;
    const int lid = t & 63, wid = t >> 6;
    const int r = blockIdx.x * 4 + wid;
    const float4* vv = (const float4*)gru_in;
    const float4* wrow = (const float4*)(W_ih + (size_t)r * H);
    float acc = 0.f;
    #pragma unroll
    for (int k = 0; k < 4; ++k) {
        int idx = k * 64 + lid;
        acc += dot4(vv[idx], wrow[idx]);
    }
    acc = wave_reduce_sum(acc);
    if (lid == 0) gx[r] = acc + b_ih[r];
}

// K5: fused GRU elementwise (redundant per block, L2-hot) + logits GEMV.
// 16 rows/block (4 waves x 4 rows), NPART blocks. Emits (max, sumexp) partials.
__global__ void k5_cell_logits(const float* __restrict__ gx,
                               const float* __restrict__ gh,
                               const float* __restrict__ hidden,
                               const float* __restrict__ out_W,
                               const float* __restrict__ out_b,
                               float* __restrict__ logits,
                               float* __restrict__ partials) {
    const int t = threadIdx.x;              // 256
    __shared__ float sh[H];
    __shared__ float sl[16];
    // h_new[4t..4t+3]
    {
        float4 xr = ((const float4*)gx)[t];
        float4 xz = ((const float4*)(gx + H))[t];
        float4 xn = ((const float4*)(gx + 2 * H))[t];
        float4 hr = ((const float4*)gh)[t];
        float4 hz = ((const float4*)(gh + H))[t];
        float4 hn = ((const float4*)(gh + 2 * H))[t];
        float4 h0 = ((const float4*)hidden)[t];
        float4 o;
        {
            float r = sigmoidf_(xr.x + hr.x), z = sigmoidf_(xz.x + hz.x);
            float n = tanhf(xn.x + r * hn.x);
            o.x = (1.f - z) * n + z * h0.x;
        }
        {
            float r = sigmoidf_(xr.y + hr.y), z = sigmoidf_(xz.y + hz.y);
            float n = tanhf(xn.y + r * hn.y);
            o.y = (1.f - z) * n + z * h0.y;
        }
        {
            float r = sigmoidf_(xr.z + hr.z), z = sigmoidf_(xz.z + hz.z);
            float n = tanhf(xn.z + r * hn.z);
            o.z = (1.f - z) * n + z * h0.z;
        }
        {
            float r = sigmoidf_(xr.w + hr.w), z = sigmoidf_(xz.w + hz.w);
            float n = tanhf(xn.w + r * hn.w);
            o.w = (1.f - z) * n + z * h0.w;
        }
        ((float4*)sh)[t] = o;
    }
    __syncthreads();
    const int lid = t & 63, wid = t >> 6;
    const float4* hv = (const float4*)sh;
    float4 h0 = hv[lid], h1 = hv[64 + lid], h2 = hv[128 + lid], h3 = hv[192 + lid];
    const int vbase = blockIdx.x * 16 + wid * 4;
    #pragma unroll
    for (int rr = 0; rr < 4; ++rr) {
        const int v = vbase + rr;
        float val = -INFINITY;
        if (v < V) {                         // wave-uniform
            const float4* wr = (const float4*)(out_W + (size_t)v * H);
            float acc = dot4(wr[lid], h0) + dot4(wr[64 + lid], h1)
                      + dot4(wr[128 + lid], h2) + dot4(wr[192 + lid], h3);
            acc = wave_reduce_sum(acc);
            if (lid == 0) { val = acc + out_b[v]; logits[v] = val; }
        }
        if (lid == 0) sl[wid * 4 + rr] = val;
    }
    __syncthreads();
    if (t == 0) {
        float M = -INFINITY;
        #pragma unroll
        for (int i = 0; i < 16; ++i) M = fmaxf(M, sl[i]);
        float S = 0.f;
        #pragma unroll
        for (int i = 0; i < 16; ++i) S += expf(sl[i] - M);
        partials[2 * blockIdx.x] = M;
        partials[2 * blockIdx.x + 1] = S;
    }
}

// K6: each block redundantly reduces partials (25 KB, L2-hot) then
// subtracts logsumexp from its 512-logit chunk.
__global__ void k6_finalize(float* __restrict__ logits,
                            const float* __restrict__ partials) {
    const int t = threadIdx.x;              // 512
    __shared__ float sm[8];
    float m = -INFINITY;
    for (int i = t; i < NPART; i += 512) m = fmaxf(m, partials[2 * i]);
    m = wave_reduce_max(m);
    if ((t & 63) == 0) sm[t >> 6] = m;
    __syncthreads();
    float M = sm[0];
    #pragma unroll
    for (int i = 1; i < 8; ++i) M = fmaxf(M, sm[i]);
    __syncthreads();
    float s = 0.f;
    for (int i = t; i < NPART; i += 512) s += partials[2 * i + 1] * expf(partials[2 * i] - M);
    s = wave_reduce_sum(s);
    if ((t & 63) == 0) sm[t >> 6] = s;
    __syncthreads();
    float S = 0.f;
    #pragma unroll
    for (int i = 0; i < 8; ++i) S += sm[i];
    const float red = M + logf(S);
    const int v = blockIdx.x * 512 + t;
    if (v < V) logits[v] -= red;
}

extern "C" void kernel_launch(void* const* d_in, const int* in_sizes, int n_in,
                              void* d_out, int out_size, void* d_ws, size_t ws_size,
                              hipStream_t stream) {
    const int*   x       = (const int*)d_in[0];
    const float* enc     = (const float*)d_in[1];
    const float* hidden  = (const float*)d_in[2];
    const float* emb     = (const float*)d_in[3];
    const float* attn_W  = (const float*)d_in[4];
    const float* attn_b  = (const float*)d_in[5];
    const float* comb_W  = (const float*)d_in[6];
    const float* comb_b  = (const float*)d_in[7];
    const float* W_ih    = (const float*)d_in[8];
    const float* W_hh    = (const float*)d_in[9];
    const float* b_ih    = (const float*)d_in[10];
    const float* b_hh    = (const float*)d_in[11];
    const float* out_W   = (const float*)d_in[12];
    const float* out_b   = (const float*)d_in[13];
    float* out = (float*)d_out;
    float* ws  = (float*)d_ws;

    float* scores   = ws;            // 512
    float* attnap   = ws + 512;      // 1024
    float* gru_in   = ws + 1536;     // 1024
    float* gx       = ws + 2560;     // 3072
    float* gh       = ws + 5632;     // 3072
    float* partials = ws + 8704;     // 2*NPART

    k1_scores_gh<<<897, 256, 0, stream>>>(x, emb, hidden, attn_W, attn_b,
                                          W_hh, b_hh, scores, gh, attnap);
    k2_softmax_apply<<<dim3(4, 16), 256, 0, stream>>>(scores, enc, attnap, out + V);
    k3_combine<<<256, 256, 0, stream>>>(x, emb, attnap, comb_W, comb_b, gru_in);
    k4_gx<<<768, 256, 0, stream>>>(W_ih, b_ih, gru_in, gx);
    k5_cell_logits<<<NPART, 256, 0, stream>>>(gx, gh, hidden, out_W, out_b, out, partials);
    k6_finalize<<<(V + 511) / 512, 512, 0, stream>>>(out, partials);
}